// Round 3
// baseline (148.561 us; speedup 1.0000x reference)
//
#include <hip/hip_runtime.h>

#define BN 2048
#define DD 128

typedef __attribute__((ext_vector_type(8))) short bf8;
typedef __attribute__((ext_vector_type(16))) float f16v;

__device__ __forceinline__ short bf16rne(float f) {
    unsigned u = __float_as_uint(f);
    u = (u + 0x7FFFu + ((u >> 16) & 1u)) >> 16;
    return (short)u;
}

__device__ __forceinline__ unsigned pk2(float a, float b) {
    return ((unsigned)(unsigned short)bf16rne(b) << 16) | (unsigned short)bf16rne(a);
}

__device__ __forceinline__ bf8 cvt8(float4 f0, float4 f1) {
    bf8 w;
    w[0] = bf16rne(f0.x); w[1] = bf16rne(f0.y);
    w[2] = bf16rne(f0.z); w[3] = bf16rne(f0.w);
    w[4] = bf16rne(f1.x); w[5] = bf16rne(f1.y);
    w[6] = bf16rne(f1.z); w[7] = bf16rne(f1.w);
    return w;
}

__device__ __forceinline__ void dma16(const void* gsrc, void* ldst) {
    __builtin_amdgcn_global_load_lds(
        (const __attribute__((address_space(1))) void*)gsrc,
        (__attribute__((address_space(3))) void*)ldst,
        16, 0, 0);
}

// wave copies its contiguous 8KB slice of a 32KB tile image
__device__ __forceinline__ void dma_tile(short* lds, const short* g, int wave, int lane) {
    const char* gp = (const char*)g + wave * 8192 + lane * 16;
    char* lp = (char*)lds + wave * 8192 + lane * 16;
    #pragma unroll
    for (int c = 0; c < 8; ++c)
        dma16(gp + c * 1024, lp + c * 1024);
}

// ---------------- pre-pass: build bf16 images in d_ws ----------------------
// K image (b,it): granule o = g*128 + r  (16B) = K[it*128+r][g*8 .. g*8+7]
// V image (b,it): granule o = kg*128 + d (16B) = { V[it*128+kg*8+j][d] } j=0..7
// Both: coalesced reads, coalesced writes, conflict-free LDS.
__launch_bounds__(256, 4)
__global__ void prep_kernel(const float* __restrict__ K, const float* __restrict__ V,
                            short* __restrict__ KS, short* __restrict__ VS) {
    __shared__ short tile[128 * 136];   // [r][d], row stride 136 shorts (16B-aligned)
    const int t = threadIdx.x;
    const int blk = blockIdx.x;
    const bool isK = blk < 256;
    const int bb = isK ? blk : blk - 256;
    const int b = bb >> 4, it = bb & 15;
    const float* src = (isK ? K : V) + ((size_t)b * BN + it * 128) * DD;

    // fill tile[r][d] (bf16), coalesced
    #pragma unroll
    for (int i = 0; i < 8; ++i) {
        int gid = t + 256 * i;
        int r = gid >> 4, g = gid & 15;
        float4 f0 = *(const float4*)(src + r * DD + g * 8);
        float4 f1 = *(const float4*)(src + r * DD + g * 8 + 4);
        *(bf8*)&tile[r * 136 + g * 8] = cvt8(f0, f1);
    }
    __syncthreads();

    if (isK) {
        short* dst = KS + (((size_t)b * 16 + it) << 14);
        #pragma unroll
        for (int i = 0; i < 8; ++i) {
            int o = t + 256 * i;
            int g = o >> 7, r = o & 127;
            *(bf8*)&dst[o * 8] = *(const bf8*)&tile[r * 136 + g * 8];
        }
    } else {
        short* dst = VS + (((size_t)b * 16 + it) << 14);
        #pragma unroll
        for (int i = 0; i < 4; ++i) {
            int p = t + 256 * i;           // granule pair id
            int kg = p >> 6;
            int d0 = (p & 63) * 2;
            bf8 w0, w1;
            #pragma unroll
            for (int j = 0; j < 8; ++j) {
                unsigned u = *(const unsigned*)&tile[(kg * 8 + j) * 136 + d0];
                w0[j] = (short)(u & 0xFFFF);
                w1[j] = (short)(u >> 16);
            }
            int o = kg * 128 + d0;
            *(bf8*)&dst[o * 8] = w0;
            *(bf8*)&dst[(o + 1) * 8] = w1;
        }
    }
}

// softmax + build PV A-operand fragments in-register from S^T C-layout.
// S^T: col = q = lane&31, row(key) = (reg&3) + 8*(reg>>2) + 4*lh.
__device__ __forceinline__ void build_frags(const f16v& s, float scl, float& l,
                                            bf8 af[2], int lh) {
    float pv[16];
    #pragma unroll
    for (int r = 0; r < 16; ++r) {
        pv[r] = __builtin_amdgcn_exp2f(s[r] * scl);
        l += pv[r];
    }
    unsigned P2[8];   // [G*2+h], G = reg quad (rows 8G+4lh+0..3)
    #pragma unroll
    for (int G = 0; G < 4; ++G) {
        P2[G * 2 + 0] = pk2(pv[4 * G + 0], pv[4 * G + 1]);
        P2[G * 2 + 1] = pk2(pv[4 * G + 2], pv[4 * G + 3]);
    }
    #pragma unroll
    for (int s2 = 0; s2 < 2; ++s2) {
        unsigned send0 = lh ? P2[4 * s2 + 0] : P2[4 * s2 + 2];
        unsigned send1 = lh ? P2[4 * s2 + 1] : P2[4 * s2 + 3];
        unsigned r0 = (unsigned)__shfl_xor((int)send0, 32, 64);
        unsigned r1 = (unsigned)__shfl_xor((int)send1, 32, 64);
        unsigned own0 = lh ? P2[4 * s2 + 2] : P2[4 * s2 + 0];
        unsigned own1 = lh ? P2[4 * s2 + 3] : P2[4 * s2 + 1];
        union { unsigned u[4]; bf8 v; } f;
        f.u[0] = lh ? r0 : own0;
        f.u[1] = lh ? r1 : own1;
        f.u[2] = lh ? own0 : r0;
        f.u[3] = lh ? own1 : r1;
        af[s2] = f.v;
    }
}

// ---------------- attention v3 --------------------------------------------
// Block: 64 q-rows. 4 waves = 4 key-quarters (32 keys each), every wave covers
// all 64 q (2 q-tiles) -> each K/V frag read feeds 2 MFMAs.
// S^T = mfma(K,Q) so P needs no LDS round-trip (shfl quad exchange instead).
__launch_bounds__(256, 2)
__global__ void attn3(const float* __restrict__ Q,
                      const short* __restrict__ KS,
                      const short* __restrict__ VS,
                      const int* __restrict__ VL,
                      float* __restrict__ O) {
    __shared__ __align__(16) char smem[65536 + 1024];
    short* sK = (short*)smem;              // 32 KB K image
    short* sV = (short*)(smem + 32768);    // 32 KB V image
    float* lSh = (float*)(smem + 65536);   // [4][64]
    float* buf4 = (float*)smem;            // epilogue: [w][64 q][64 d] f32 (64 KB)

    const int tid  = threadIdx.x;
    const int wave = tid >> 6;
    const int lane = tid & 63;
    const int lw   = lane & 31;
    const int lh   = lane >> 5;
    const int kq   = wave;        // key quarter
    const int kt   = kq * 32;

    const int L  = blockIdx.x;
    const int b  = (L & 7) | (((L >> 3) & 1) << 3);
    const int qt0 = L >> 4;
    const int q0 = qt0 * 64;

    const int vlen = VL[b];
    constexpr float SCL2 = 1.4426950408889634f * 0.08838834764831845f; // log2e/sqrt(128)

    const float scl0 = (q0 + lw      >= vlen) ? 0.0f : SCL2;
    const float scl1 = (q0 + 32 + lw >= vlen) ? 0.0f : SCL2;

    const short* kbase = KS + (((size_t)b * 16) << 14);
    const short* vbase = VS + (((size_t)b * 16) << 14);

    dma_tile(sK, kbase, wave, lane);   // sK(0) in flight

    // Q fragments, B-layout: lane n=q holds d = ks*16 + lh*8 + j
    bf8 qfrag[2][8];
    #pragma unroll
    for (int qt = 0; qt < 2; ++qt) {
        const float* qp = Q + ((size_t)b * BN + q0 + qt * 32 + lw) * DD;
        #pragma unroll
        for (int ks = 0; ks < 8; ++ks) {
            int d0 = ks * 16 + lh * 8;
            float4 f0 = *(const float4*)(qp + d0);
            float4 f1 = *(const float4*)(qp + d0 + 4);
            qfrag[qt][ks] = cvt8(f0, f1);
        }
    }

    f16v oacc[2][4] = {};
    float l0 = 0.0f, l1 = 0.0f;

    for (int it = 0; it < 16; ++it) {
        __syncthreads();                                       // sK(it) ready
        dma_tile(sV, vbase + ((size_t)it << 14), wave, lane);  // fly during QK

        // ---- S^T = K Q^T : 2 q-tiles share each K frag
        f16v s0 = {}, s1 = {};
        #pragma unroll
        for (int ks = 0; ks < 8; ++ks) {
            const bf8 kf = *(const bf8*)&sK[(((ks * 2 + lh) << 7) + kt + lw) * 8];
            s0 = __builtin_amdgcn_mfma_f32_32x32x16_bf16(kf, qfrag[0][ks], s0, 0, 0, 0);
            s1 = __builtin_amdgcn_mfma_f32_32x32x16_bf16(kf, qfrag[1][ks], s1, 0, 0, 0);
        }

        // ---- softmax + in-register P fragments
        bf8 af0[2], af1[2];
        build_frags(s0, scl0, l0, af0, lh);
        build_frags(s1, scl1, l1, af1, lh);

        __syncthreads();                                       // sV(it) ready
        if (it < 15)
            dma_tile(sK, kbase + ((size_t)(it + 1) << 14), wave, lane);  // fly during PV

        // ---- O += P V : 2 q-tiles share each V frag
        #pragma unroll
        for (int s = 0; s < 2; ++s) {
            #pragma unroll
            for (int ot = 0; ot < 4; ++ot) {
                const bf8 vf = *(const bf8*)&sV[(((kq * 4 + 2 * s + lh) << 7) + ot * 32 + lw) * 8];
                oacc[0][ot] = __builtin_amdgcn_mfma_f32_32x32x16_bf16(af0[s], vf, oacc[0][ot], 0, 0, 0);
                oacc[1][ot] = __builtin_amdgcn_mfma_f32_32x32x16_bf16(af1[s], vf, oacc[1][ot], 0, 0, 0);
            }
        }
    }

    // ---- epilogue: combine 4 key-quarter partials via 2 d-half phases
    l0 += __shfl_xor(l0, 32, 64);
    l1 += __shfl_xor(l1, 32, 64);
    __syncthreads();   // all PV reads done before smem reuse
    if (lh == 0) {
        lSh[wave * 64 + lw] = l0;
        lSh[wave * 64 + 32 + lw] = l1;
    }

    const size_t orow0 = (size_t)b * BN + q0;
    #pragma unroll
    for (int half = 0; half < 2; ++half) {
        // write partials for d in [half*64, half*64+64)
        #pragma unroll
        for (int qt = 0; qt < 2; ++qt) {
            #pragma unroll
            for (int oi = 0; oi < 2; ++oi) {
                int ot = half * 2 + oi;
                #pragma unroll
                for (int reg = 0; reg < 16; ++reg) {
                    int row = (reg & 3) + 8 * (reg >> 2) + 4 * lh;
                    buf4[wave * 4096 + (qt * 32 + row) * 64 + oi * 32 + lw] =
                        oacc[qt][ot][reg];
                }
            }
        }
        __syncthreads();
        // each wave reduces 16 q-rows across the 4 partials and stores
        #pragma unroll
        for (int i = 0; i < 16; ++i) {
            int q = wave * 16 + i;
            float ltot = lSh[q] + lSh[64 + q] + lSh[128 + q] + lSh[192 + q];
            float rinv = __builtin_amdgcn_rcpf(ltot);
            float v = buf4[q * 64 + lane] + buf4[4096 + q * 64 + lane] +
                      buf4[8192 + q * 64 + lane] + buf4[12288 + q * 64 + lane];
            O[(orow0 + q) * DD + half * 64 + lane] = v * rinv;
        }
        __syncthreads();
    }
}

// ---------------- fallback (no workspace): correct but slow -----------------
__launch_bounds__(256, 2)
__global__ void attn_fallback(const float* __restrict__ Q,
                              const float* __restrict__ K,
                              const float* __restrict__ V,
                              const int* __restrict__ VL,
                              float* __restrict__ O) {
    // one block per (b, 16 q-rows); simple vector kernel
    const int b = blockIdx.x >> 7;
    const int q = ((blockIdx.x & 127) * 16) + (threadIdx.x >> 4);
    const int dl = (threadIdx.x & 15) * 8;
    const int vlen = VL[b];
    const float scl = (q >= vlen) ? 0.0f : (1.4426950408889634f * 0.08838834764831845f);
    const float* qp = Q + ((size_t)b * BN + q) * DD;
    float acc[8] = {};
    float l = 0.0f;
    for (int k = 0; k < BN; ++k) {
        const float* kp = K + ((size_t)b * BN + k) * DD;
        float s = 0.0f;
        for (int d = 0; d < DD; ++d) s += qp[d] * kp[d];
        float p = __builtin_amdgcn_exp2f(s * scl);
        l += p;
        const float* vp = V + ((size_t)b * BN + k) * DD + dl;
        #pragma unroll
        for (int e = 0; e < 8; ++e) acc[e] += p * vp[e];
    }
    float* op = O + ((size_t)b * BN + q) * DD + dl;
    #pragma unroll
    for (int e = 0; e < 8; ++e) op[e] = acc[e] / l;
}

extern "C" void kernel_launch(void* const* d_in, const int* in_sizes, int n_in,
                              void* d_out, int out_size, void* d_ws, size_t ws_size,
                              hipStream_t stream) {
    const float* Q  = (const float*)d_in[0];
    const float* K  = (const float*)d_in[1];
    const float* V  = (const float*)d_in[2];
    const int*   VL = (const int*)d_in[3];
    float* O = (float*)d_out;

    const size_t need = (size_t)2 * 16 * 16 * 16384 * sizeof(short);  // 16 MB
    if (ws_size >= need) {
        short* KS = (short*)d_ws;
        short* VS = KS + (size_t)16 * 16 * 16384;
        prep_kernel<<<512, 256, 0, stream>>>(K, V, KS, VS);
        attn3<<<512, 256, 0, stream>>>(Q, KS, VS, VL, O);
    } else {
        attn_fallback<<<2048, 256, 0, stream>>>(Q, K, V, VL, O);
    }
}